// Round 7
// baseline (858.065 us; speedup 1.0000x reference)
//
#include <hip/hip_runtime.h>
#include <hip/hip_bf16.h>

#define B_ 8
#define C_ 64
#define N_ 4096
#define K_ 20
#define O_ 64

constexpr float BN_EPS = 1e-5f;
constexpr float NEG = 0.2f;
constexpr int ROWS = B_ * N_;        // 32768
constexpr int M_TOT = ROWS * K_;     // 655360
constexpr int RT = 4;                // q rows per wave in knn

__device__ __forceinline__ float readlane_f(float v, int src) {
  return __int_as_float(__builtin_amdgcn_readlane(__float_as_int(v), src));
}

// ----------------------------------------------------------------------------
// ws layout (float elements):
//   y   : [0,        2097152)   y[b][n][o]  = xt[b,n,:]  . W1[o,:]
//   z   : [2097152,  4194304)   z[b][n][o]  = xt[b,n,:]  . (W2-W1)[o,:]
//   xx  : [4194304,  4227072)   xx[b][n]    = ||xt[b,n,:]||^2
//   idx : [4227072,  4882432)   (int) idx[b][n][k]
//   s1/s2/sc/sh : 64 floats each after that
// ----------------------------------------------------------------------------

__global__ __launch_bounds__(256) void prep_kernel(const float* __restrict__ x,
                                                   const float* __restrict__ W,
                                                   float* __restrict__ y,
                                                   float* __restrict__ z,
                                                   float* __restrict__ xx) {
  __shared__ float xt[64][65];  // [n_local][c]
  __shared__ float w1[64][65];  // [o][c]   = W[o][c]
  __shared__ float wd[64][65];  // [o][c]   = W[o][64+c] - W[o][c]
  const int b = blockIdx.x >> 6;
  const int n0 = (blockIdx.x & 63) << 6;
  const int tid = threadIdx.x;

  for (int rep = 0; rep < 16; ++rep) {
    int id = rep * 256 + tid;
    int cc = id >> 6, nl = id & 63;
    xt[nl][cc] = x[((b * 64 + cc) << 12) + n0 + nl];  // coalesced over nl
    int o = cc, c = nl;
    float a = W[o * 128 + c];
    float bb = W[o * 128 + 64 + c];
    w1[o][c] = a;
    wd[o][c] = bb - a;
  }
  __syncthreads();

  const int o = tid & 63;
  for (int nl = tid >> 6; nl < 64; nl += 4) {
    float ay = 0.f, az = 0.f;
#pragma unroll 8
    for (int c = 0; c < 64; ++c) {
      float v = xt[nl][c];
      ay = fmaf(v, w1[o][c], ay);
      az = fmaf(v, wd[o][c], az);
    }
    int gi = (((b << 12) + n0 + nl) << 6) + o;
    y[gi] = ay;
    z[gi] = az;
  }
  if (tid < 64) {
    float s = 0.f;
#pragma unroll 8
    for (int c = 0; c < 64; ++c) {
      float v = xt[tid][c];
      s = fmaf(v, v, s);
    }
    xx[(b << 12) + n0 + tid] = s;
  }
}

// knn v7 = v6 with register headroom. v6's __launch_bounds__(256,8) forced
// VGPR_Count=32 (static demand >=50) -> register-starved codegen (~2.5x VALU
// inflation per rocprof). (256,6) caps at ~85 VGPR / 6 waves per SIMD;
// unroll 8 keeps 8 xj loads in flight. Algorithm + numerics identical to v6
// -> identical neighbor sets.
__global__ __launch_bounds__(256, 6) void knn_kernel(const float* __restrict__ x,
                                                     const float* __restrict__ xx,
                                                     int* __restrict__ idx) {
  const int tid = threadIdx.x;
  const int w = tid >> 6;              // wave 0..3
  const int lane = tid & 63;
  const int row0 = blockIdx.x * 16 + 4 * w;  // this wave's 4 rows
  const int b = row0 >> 12;
  const int i0 = row0 & 4095;
  const float* xb = x + ((size_t)b << 18);   // b*64*4096
  const float* xxb = xx + (b << 12);

  __shared__ float4 xi4[4][64];        // [wave][c] = xq rows 0..3 at channel c

  // one-time staging: lane c loads this wave's 4 consecutive rows at channel c
  xi4[w][lane] = *(const float4*)(xb + ((size_t)lane << 12) + i0);
  // written and read by the same wave only -> no barrier needed

  float bv[RT], T[RT];
  int bi[RT];
#pragma unroll
  for (int r = 0; r < RT; ++r) {
    bv[r] = __builtin_inff();
    T[r] = __builtin_inff();
    bi[r] = 0;
  }

  for (int jb = 0; jb < N_; jb += 256) {
    const int j0 = jb + (lane << 2);
    float4 xxj = *(const float4*)(xxb + j0);   // in flight during compute
    float4 acc[RT];
#pragma unroll
    for (int r = 0; r < RT; ++r) acc[r] = make_float4(0.f, 0.f, 0.f, 0.f);
    const float* xp = xb + j0;
#pragma unroll 8
    for (int c = 0; c < 64; ++c) {
      float4 xj = *(const float4*)(xp + ((size_t)c << 12));
      float4 xa = xi4[w][c];           // same-addr wave broadcast (1 b128)
      acc[0].x = fmaf(xa.x, xj.x, acc[0].x);
      acc[0].y = fmaf(xa.x, xj.y, acc[0].y);
      acc[0].z = fmaf(xa.x, xj.z, acc[0].z);
      acc[0].w = fmaf(xa.x, xj.w, acc[0].w);
      acc[1].x = fmaf(xa.y, xj.x, acc[1].x);
      acc[1].y = fmaf(xa.y, xj.y, acc[1].y);
      acc[1].z = fmaf(xa.y, xj.z, acc[1].z);
      acc[1].w = fmaf(xa.y, xj.w, acc[1].w);
      acc[2].x = fmaf(xa.z, xj.x, acc[2].x);
      acc[2].y = fmaf(xa.z, xj.y, acc[2].y);
      acc[2].z = fmaf(xa.z, xj.z, acc[2].z);
      acc[2].w = fmaf(xa.z, xj.w, acc[2].w);
      acc[3].x = fmaf(xa.w, xj.x, acc[3].x);
      acc[3].y = fmaf(xa.w, xj.y, acc[3].y);
      acc[3].z = fmaf(xa.w, xj.z, acc[3].z);
      acc[3].w = fmaf(xa.w, xj.w, acc[3].w);
    }
#pragma unroll
    for (int r = 0; r < RT; ++r) {
      float dv[4] = {xxj.x - 2.f * acc[r].x, xxj.y - 2.f * acc[r].y,
                     xxj.z - 2.f * acc[r].z, xxj.w - 2.f * acc[r].w};
#pragma unroll
      for (int jj = 0; jj < 4; ++jj) {
        float v = dv[jj];
        unsigned long long rem = 0xFFFFFFFFFFFFFFFFull;
        while (true) {
          unsigned long long m = __ballot(v < T[r]) & rem;
          if (!m) break;
          int src = __ffsll(m) - 1;
          rem &= ~(1ull << src);
          float cv = readlane_f(v, src);               // VALU broadcast
          int cj = __builtin_amdgcn_readlane(j0 + jj, src);
          // fresh ballot guarantees cv < T -> unconditional insert
          unsigned long long le = __ballot(bv[r] <= cv) & 0xFFFFFull;
          int pos = __popcll(le);
          float pv = __shfl_up(bv[r], 1);
          int pi = __shfl_up(bi[r], 1);
          if (lane >= pos) {
            bool ins = (lane == pos);
            bv[r] = ins ? cv : pv;
            bi[r] = ins ? cj : pi;
          }
          T[r] = readlane_f(bv[r], K_ - 1);
        }
      }
    }
  }

#pragma unroll
  for (int r = 0; r < RT; ++r) {
    if (lane < K_) idx[(row0 + r) * K_ + lane] = bi[r];
  }
}

__global__ __launch_bounds__(256) void stats_kernel(const float* __restrict__ y,
                                                    const float* __restrict__ z,
                                                    const int* __restrict__ idx,
                                                    float* __restrict__ s1,
                                                    float* __restrict__ s2) {
  const int tid = threadIdx.x;
  const int o = tid & 63;
  const int r = tid >> 6;
  const int row0 = blockIdx.x << 6;  // 64 rows per block
  float a1 = 0.f, a2 = 0.f;
  for (int rl = r; rl < 64; rl += 4) {
    const int row = row0 + rl;
    const int b = row >> 12;
    const float zv = z[(row << 6) + o];
    const int* ip = idx + row * K_;
    const float* yb = y + ((size_t)b << 18);
    float s1r = 0.f;
#pragma unroll
    for (int k = 0; k < K_; ++k) {
      int j = ip[k];
      float h = yb[(j << 6) + o] + zv;
      s1r += h;
      a2 = fmaf(h, h, a2);
    }
    a1 += s1r;
  }
  __shared__ float r1[4][64];
  __shared__ float r2[4][64];
  r1[r][o] = a1;
  r2[r][o] = a2;
  __syncthreads();
  if (tid < 64) {
    float t1 = r1[0][tid] + r1[1][tid] + r1[2][tid] + r1[3][tid];
    float t2 = r2[0][tid] + r2[1][tid] + r2[2][tid] + r2[3][tid];
    atomicAdd(&s1[tid], t1);
    atomicAdd(&s2[tid], t2);
  }
}

__global__ void finalize_kernel(const float* __restrict__ s1,
                                const float* __restrict__ s2,
                                const float* __restrict__ gamma,
                                const float* __restrict__ beta,
                                float* __restrict__ sc,
                                float* __restrict__ sh) {
  int o = threadIdx.x;
  float mean = s1[o] / (float)M_TOT;
  float var = s2[o] / (float)M_TOT - mean * mean;
  float inv = 1.0f / sqrtf(var + BN_EPS);
  float s = gamma[o] * inv;
  sc[o] = s;
  sh[o] = beta[o] - mean * s;
}

__global__ __launch_bounds__(256) void out_kernel(const float* __restrict__ y,
                                                  const float* __restrict__ z,
                                                  const int* __restrict__ idx,
                                                  const float* __restrict__ sc,
                                                  const float* __restrict__ sh,
                                                  float* __restrict__ out) {
  __shared__ float til[64][65];  // [o][n_local]
  const int tid = threadIdx.x;
  const int b = blockIdx.x >> 6;
  const int n0 = (blockIdx.x & 63) << 6;
  const int o = tid & 63;
  const float s = sc[o];
  const float t = sh[o];
  const float* yb = y + ((size_t)b << 18);

  for (int nl = tid >> 6; nl < 64; nl += 4) {
    const int row = (b << 12) + n0 + nl;
    const float zv = z[(row << 6) + o];
    const int* ip = idx + row * K_;
    float m = -__builtin_inff();
#pragma unroll
    for (int k = 0; k < K_; ++k) {
      int j = ip[k];
      float h = yb[(j << 6) + o] + zv;
      float hn = fmaf(h, s, t);
      float a = hn >= 0.f ? hn : NEG * hn;
      m = fmaxf(m, a);
    }
    til[o][nl] = m;
  }
  __syncthreads();
  for (int rep = 0; rep < 16; ++rep) {
    int id = rep * 256 + tid;
    int oo = id >> 6, nl = id & 63;
    out[((size_t)((b << 6) + oo) << 12) + n0 + nl] = til[oo][nl];
  }
}

extern "C" void kernel_launch(void* const* d_in, const int* in_sizes, int n_in,
                              void* d_out, int out_size, void* d_ws, size_t ws_size,
                              hipStream_t stream) {
  const float* x = (const float*)d_in[0];
  const float* W = (const float*)d_in[1];
  const float* gamma = (const float*)d_in[2];
  const float* beta = (const float*)d_in[3];
  float* ws = (float*)d_ws;
  float* y = ws;
  float* z = ws + 2097152;
  float* xx = ws + 4194304;
  int* idxp = (int*)(ws + 4227072);
  float* s1 = ws + 4882432;
  float* s2 = ws + 4882496;
  float* sc = ws + 4882560;
  float* sh = ws + 4882624;
  float* out = (float*)d_out;

  hipMemsetAsync(s1, 0, 2 * 64 * sizeof(float), stream);

  prep_kernel<<<512, 256, 0, stream>>>(x, W, y, z, xx);
  knn_kernel<<<ROWS / 16, 256, 0, stream>>>(x, xx, idxp);
  stats_kernel<<<512, 256, 0, stream>>>(y, z, idxp, s1, s2);
  finalize_kernel<<<1, 64, 0, stream>>>(s1, s2, gamma, beta, sc, sh);
  out_kernel<<<512, 256, 0, stream>>>(y, z, idxp, sc, sh, out);
}

// Round 8
// 487.429 us; speedup vs baseline: 1.7604x; 1.7604x over previous
//
#include <hip/hip_runtime.h>
#include <hip/hip_bf16.h>

#define B_ 8
#define C_ 64
#define N_ 4096
#define K_ 20
#define O_ 64

typedef unsigned short ushort_t;
typedef __attribute__((ext_vector_type(8))) short bf16x8;
typedef __attribute__((ext_vector_type(16))) float f32x16;

constexpr float BN_EPS = 1e-5f;
constexpr float NEG = 0.2f;
constexpr int ROWS = B_ * N_;        // 32768
constexpr int M_TOT = ROWS * K_;     // 655360

__device__ __forceinline__ float readlane_f(float v, int src) {
  return __int_as_float(__builtin_amdgcn_readlane(__float_as_int(v), src));
}

// RNE float -> bf16 bits
__device__ __forceinline__ unsigned int bf16_rne(float v) {
  unsigned int u = __float_as_uint(v);
  return (u + 0x7FFFu + ((u >> 16) & 1u)) >> 16;
}

// ----------------------------------------------------------------------------
// ws layout (float elements):
//   y   : [0,        2097152)   y[b][n][o]  = xt[b,n,:] . W1[o,:]
//   z   : [2097152,  4194304)   z[b][n][o]  = xt[b,n,:] . (W2-W1)[o,:]
//   xx  : [4194304,  4227072)   xx[b][n]    = ||xt[b,n,:]||^2
//   idx : [4227072,  4882432)   (int) idx[b][n][k]
//   s1/s2/sc/sh : [4882432, 4882688)
//   xh  : [4882688,  5931264)   bf16[b][n][c] (as ushort), high split
//   xl  : [5931264,  6979840)   bf16 mid split
//   xq  : [6979840,  8028416)   bf16 low split      (~32.1 MB total)
// ----------------------------------------------------------------------------

__global__ __launch_bounds__(256) void prep_kernel(const float* __restrict__ x,
                                                   const float* __restrict__ W,
                                                   float* __restrict__ y,
                                                   float* __restrict__ z,
                                                   float* __restrict__ xx,
                                                   ushort_t* __restrict__ xh,
                                                   ushort_t* __restrict__ xl,
                                                   ushort_t* __restrict__ xq) {
  __shared__ float xt[64][65];  // [n_local][c]
  __shared__ float w1[64][65];  // [o][c]   = W[o][c]
  __shared__ float wd[64][65];  // [o][c]   = W[o][64+c] - W[o][c]
  const int b = blockIdx.x >> 6;
  const int n0 = (blockIdx.x & 63) << 6;
  const int tid = threadIdx.x;

  for (int rep = 0; rep < 16; ++rep) {
    int id = rep * 256 + tid;
    int cc = id >> 6, nl = id & 63;
    xt[nl][cc] = x[((b * 64 + cc) << 12) + n0 + nl];  // coalesced over nl
    int o = cc, c = nl;
    float a = W[o * 128 + c];
    float bb = W[o * 128 + 64 + c];
    w1[o][c] = a;
    wd[o][c] = bb - a;
  }
  __syncthreads();

  const int o = tid & 63;
  for (int nl = tid >> 6; nl < 64; nl += 4) {
    float ay = 0.f, az = 0.f;
#pragma unroll 8
    for (int c = 0; c < 64; ++c) {
      float v = xt[nl][c];
      ay = fmaf(v, w1[o][c], ay);
      az = fmaf(v, wd[o][c], az);
    }
    int gi = (((b << 12) + n0 + nl) << 6) + o;
    y[gi] = ay;
    z[gi] = az;
  }
  if (tid < 64) {
    float s = 0.f;
#pragma unroll 8
    for (int c = 0; c < 64; ++c) {
      float v = xt[tid][c];
      s = fmaf(v, v, s);
    }
    xx[(b << 12) + n0 + tid] = s;
  }

  // 3-way bf16 split, transposed layout [b][n][c] for MFMA fragment loads
  for (int rep = 0; rep < 16; ++rep) {
    int id = rep * 256 + tid;
    int c = id & 63, nl = id >> 6;
    float v = xt[nl][c];
    unsigned int hb = bf16_rne(v);
    float hf = __uint_as_float(hb << 16);
    float r1 = v - hf;
    unsigned int lb = bf16_rne(r1);
    float lf = __uint_as_float(lb << 16);
    unsigned int qb = bf16_rne(r1 - lf);
    size_t gi = (((size_t)(b << 12) + n0 + nl) << 6) + c;  // coalesced over c
    xh[gi] = (ushort_t)hb;
    xl[gi] = (ushort_t)lb;
    xq[gi] = (ushort_t)qb;
  }
}

// knn v8: MFMA distances. Block = 32-row i-strip; 4 waves each compute a
// 32x32 tile of the 128-j macro-tile via mfma_f32_32x32x16_bf16 with a
// 3-way bf16 split (hh/hl/lh/hq/qh/ll -> error below fp32-chain noise).
// Tiles finalize (xx[j]-2*acc, verified C layout), round-trip through LDS,
// then the proven r6 fresh-ballot selection runs per wave on 8 owned rows
// (ascending j -> stable ties, same semantics as v6/v7).
__global__ __launch_bounds__(256) void knn_kernel(const ushort_t* __restrict__ xh,
                                                  const ushort_t* __restrict__ xl,
                                                  const ushort_t* __restrict__ xq,
                                                  const float* __restrict__ xx,
                                                  int* __restrict__ idx) {
  const int tid = threadIdx.x;
  const int w = tid >> 6;
  const int lane = tid & 63;
  const int b = blockIdx.x >> 7;
  const int i0 = (blockIdx.x & 127) << 5;
  const int half = lane >> 5;    // 0..1
  const int mcol = lane & 31;

  __shared__ float Dld[32 * 132];  // [row][128 j + pad]

  // A fragments (constant per block): 3 splits x 4 c-chunks
  bf16x8 Ah[4], Al[4], Aq[4];
  {
    const size_t rowbase = (((size_t)(b << 12)) + i0 + mcol) << 6;
    const int koff = half << 3;
#pragma unroll
    for (int cc = 0; cc < 4; ++cc) {
      size_t off = rowbase + cc * 16 + koff;
      Ah[cc] = *(const bf16x8*)(xh + off);
      Al[cc] = *(const bf16x8*)(xl + off);
      Aq[cc] = *(const bf16x8*)(xq + off);
    }
  }

  float bv[8], T[8];
  int bi[8];
#pragma unroll
  for (int r = 0; r < 8; ++r) {
    bv[r] = __builtin_inff();
    T[r] = __builtin_inff();
    bi[r] = 0;
  }

  const float* xxb = xx + (b << 12);

  for (int jb = 0; jb < N_; jb += 128) {
    const int jq0 = jb + (w << 5);  // this wave's 32-j quarter
    bf16x8 Bh[4], Bl[4], Bq[4];
    {
      const size_t colbase = (((size_t)(b << 12)) + jq0 + mcol) << 6;
      const int koff = half << 3;
#pragma unroll
      for (int cc = 0; cc < 4; ++cc) {
        size_t off = colbase + cc * 16 + koff;
        Bh[cc] = *(const bf16x8*)(xh + off);
        Bl[cc] = *(const bf16x8*)(xl + off);
        Bq[cc] = *(const bf16x8*)(xq + off);
      }
    }
    f32x16 acc;
#pragma unroll
    for (int t = 0; t < 16; ++t) acc[t] = 0.f;
#pragma unroll
    for (int cc = 0; cc < 4; ++cc) {
      acc = __builtin_amdgcn_mfma_f32_32x32x16_bf16(Ah[cc], Bh[cc], acc, 0, 0, 0);
      acc = __builtin_amdgcn_mfma_f32_32x32x16_bf16(Ah[cc], Bl[cc], acc, 0, 0, 0);
      acc = __builtin_amdgcn_mfma_f32_32x32x16_bf16(Al[cc], Bh[cc], acc, 0, 0, 0);
      acc = __builtin_amdgcn_mfma_f32_32x32x16_bf16(Ah[cc], Bq[cc], acc, 0, 0, 0);
      acc = __builtin_amdgcn_mfma_f32_32x32x16_bf16(Aq[cc], Bh[cc], acc, 0, 0, 0);
      acc = __builtin_amdgcn_mfma_f32_32x32x16_bf16(Al[cc], Bl[cc], acc, 0, 0, 0);
    }
    const float xxv = xxb[jq0 + mcol];
#pragma unroll
    for (int t = 0; t < 16; ++t) {
      int row = (t & 3) + ((t >> 2) << 3) + (half << 2);  // verified C layout
      Dld[row * 132 + (w << 5) + mcol] = fmaf(-2.f, acc[t], xxv);
    }
    __syncthreads();

    // selection: wave owns rows w*8 .. w*8+7, scans 128 j in two 64-lane segs
#pragma unroll
    for (int r = 0; r < 8; ++r) {
      const int row = (w << 3) + r;
#pragma unroll
      for (int seg = 0; seg < 2; ++seg) {
        float v = Dld[row * 132 + (seg << 6) + lane];
        int jlane = jb + (seg << 6) + lane;
        unsigned long long rem = 0xFFFFFFFFFFFFFFFFull;
        while (true) {
          unsigned long long m = __ballot(v < T[r]) & rem;
          if (!m) break;
          int src = __ffsll(m) - 1;
          rem &= ~(1ull << src);
          float cv = readlane_f(v, src);
          int cj = __builtin_amdgcn_readlane(jlane, src);
          unsigned long long le = __ballot(bv[r] <= cv) & 0xFFFFFull;
          int pos = __popcll(le);
          float pv = __shfl_up(bv[r], 1);
          int pi = __shfl_up(bi[r], 1);
          if (lane >= pos) {
            bool ins = (lane == pos);
            bv[r] = ins ? cv : pv;
            bi[r] = ins ? cj : pi;
          }
          T[r] = readlane_f(bv[r], K_ - 1);
        }
      }
    }
    __syncthreads();
  }

#pragma unroll
  for (int r = 0; r < 8; ++r) {
    if (lane < K_) idx[((b << 12) + i0 + (w << 3) + r) * K_ + lane] = bi[r];
  }
}

__global__ __launch_bounds__(256) void stats_kernel(const float* __restrict__ y,
                                                    const float* __restrict__ z,
                                                    const int* __restrict__ idx,
                                                    float* __restrict__ s1,
                                                    float* __restrict__ s2) {
  const int tid = threadIdx.x;
  const int o = tid & 63;
  const int r = tid >> 6;
  const int row0 = blockIdx.x << 6;  // 64 rows per block
  float a1 = 0.f, a2 = 0.f;
  for (int rl = r; rl < 64; rl += 4) {
    const int row = row0 + rl;
    const int b = row >> 12;
    const float zv = z[(row << 6) + o];
    const int* ip = idx + row * K_;
    const float* yb = y + ((size_t)b << 18);
    float s1r = 0.f;
#pragma unroll
    for (int k = 0; k < K_; ++k) {
      int j = ip[k];
      float h = yb[(j << 6) + o] + zv;
      s1r += h;
      a2 = fmaf(h, h, a2);
    }
    a1 += s1r;
  }
  __shared__ float r1[4][64];
  __shared__ float r2[4][64];
  r1[r][o] = a1;
  r2[r][o] = a2;
  __syncthreads();
  if (tid < 64) {
    float t1 = r1[0][tid] + r1[1][tid] + r1[2][tid] + r1[3][tid];
    float t2 = r2[0][tid] + r2[1][tid] + r2[2][tid] + r2[3][tid];
    atomicAdd(&s1[tid], t1);
    atomicAdd(&s2[tid], t2);
  }
}

__global__ void finalize_kernel(const float* __restrict__ s1,
                                const float* __restrict__ s2,
                                const float* __restrict__ gamma,
                                const float* __restrict__ beta,
                                float* __restrict__ sc,
                                float* __restrict__ sh) {
  int o = threadIdx.x;
  float mean = s1[o] / (float)M_TOT;
  float var = s2[o] / (float)M_TOT - mean * mean;
  float inv = 1.0f / sqrtf(var + BN_EPS);
  float s = gamma[o] * inv;
  sc[o] = s;
  sh[o] = beta[o] - mean * s;
}

__global__ __launch_bounds__(256) void out_kernel(const float* __restrict__ y,
                                                  const float* __restrict__ z,
                                                  const int* __restrict__ idx,
                                                  const float* __restrict__ sc,
                                                  const float* __restrict__ sh,
                                                  float* __restrict__ out) {
  __shared__ float til[64][65];  // [o][n_local]
  const int tid = threadIdx.x;
  const int b = blockIdx.x >> 6;
  const int n0 = (blockIdx.x & 63) << 6;
  const int o = tid & 63;
  const float s = sc[o];
  const float t = sh[o];
  const float* yb = y + ((size_t)b << 18);

  for (int nl = tid >> 6; nl < 64; nl += 4) {
    const int row = (b << 12) + n0 + nl;
    const float zv = z[(row << 6) + o];
    const int* ip = idx + row * K_;
    float m = -__builtin_inff();
#pragma unroll
    for (int k = 0; k < K_; ++k) {
      int j = ip[k];
      float h = yb[(j << 6) + o] + zv;
      float hn = fmaf(h, s, t);
      float a = hn >= 0.f ? hn : NEG * hn;
      m = fmaxf(m, a);
    }
    til[o][nl] = m;
  }
  __syncthreads();
  for (int rep = 0; rep < 16; ++rep) {
    int id = rep * 256 + tid;
    int oo = id >> 6, nl = id & 63;
    out[((size_t)((b << 6) + oo) << 12) + n0 + nl] = til[oo][nl];
  }
}

extern "C" void kernel_launch(void* const* d_in, const int* in_sizes, int n_in,
                              void* d_out, int out_size, void* d_ws, size_t ws_size,
                              hipStream_t stream) {
  const float* x = (const float*)d_in[0];
  const float* W = (const float*)d_in[1];
  const float* gamma = (const float*)d_in[2];
  const float* beta = (const float*)d_in[3];
  float* ws = (float*)d_ws;
  float* y = ws;
  float* z = ws + 2097152;
  float* xx = ws + 4194304;
  int* idxp = (int*)(ws + 4227072);
  float* s1 = ws + 4882432;
  float* s2 = ws + 4882496;
  float* sc = ws + 4882560;
  float* sh = ws + 4882624;
  ushort_t* xh = (ushort_t*)(ws + 4882688);
  ushort_t* xl = (ushort_t*)(ws + 5931264);
  ushort_t* xq = (ushort_t*)(ws + 6979840);
  float* out = (float*)d_out;

  hipMemsetAsync(s1, 0, 2 * 64 * sizeof(float), stream);

  prep_kernel<<<512, 256, 0, stream>>>(x, W, y, z, xx, xh, xl, xq);
  knn_kernel<<<B_ * 128, 256, 0, stream>>>(xh, xl, xq, xx, idxp);
  stats_kernel<<<512, 256, 0, stream>>>(y, z, idxp, s1, s2);
  finalize_kernel<<<1, 64, 0, stream>>>(s1, s2, gamma, beta, sc, sh);
  out_kernel<<<512, 256, 0, stream>>>(y, z, idxp, sc, sh, out);
}